// Round 4
// baseline (1498.620 us; speedup 1.0000x reference)
//
#include <hip/hip_runtime.h>
#include <stdint.h>

#define N_NODES  100000
#define N_EDGES  1600000
#define IN_FEATS 128
#define HID      32
#define N_REL    5
#define N_BASES  2
#define N_PAIRS  4096

#define NB        196        // buckets of 512 dst nodes: ceil(100000/512)
#define BSCAT_BLOCKS 391     // ceil(1600000/4096)

__device__ inline unsigned int pack_bf16(float a, float b) {
    unsigned int ua = __float_as_uint(a), ub = __float_as_uint(b);
    ua = (ua + 0x7fffu + ((ua >> 16) & 1u)) >> 16;
    ub = (ub + 0x7fffu + ((ub >> 16) & 1u)) >> 16;
    return ua | (ub << 16);
}

// ---------------- coarse bucket sort ----------------

__global__ __launch_bounds__(256) void k_bcount(const int* __restrict__ dst,
                                                int* __restrict__ ghist) {
    __shared__ int lh[NB];
    int t = threadIdx.x;
    for (int i = t; i < NB; i += 256) lh[i] = 0;
    __syncthreads();
    int e0 = blockIdx.x * 4096;
#pragma unroll
    for (int i = 0; i < 16; i++) {
        int e = e0 + t + i * 256;
        if (e < N_EDGES) atomicAdd(&lh[dst[e] >> 9], 1);
    }
    __syncthreads();
    for (int i = t; i < NB; i += 256) {
        int c = lh[i];
        if (c) atomicAdd(&ghist[i], c);
    }
}

__global__ void k_bscan(const int* __restrict__ ghist, int* __restrict__ bases,
                        int* __restrict__ gcur) {
    __shared__ int s[256];
    int t = threadIdx.x;
    int v = (t < NB) ? ghist[t] : 0;
    s[t] = v;
    __syncthreads();
    for (int off = 1; off < 256; off <<= 1) {
        int u = (t >= off) ? s[t - off] : 0;
        __syncthreads();
        s[t] += u;
        __syncthreads();
    }
    if (t < NB) {
        int excl = s[t] - v;
        bases[t] = excl;
        gcur[t]  = excl;
    }
    if (t == 0) bases[NB] = N_EDGES;
}

// record: x = (dst&511)<<23 | (src*80 + etype*16), y = mask fp32
__global__ __launch_bounds__(256) void k_bscatter(
    const int* __restrict__ src, const int* __restrict__ dst,
    const int* __restrict__ etype, const float* __restrict__ mask,
    int* __restrict__ gcur, int2* __restrict__ ebuf) {
    __shared__ int lh[NB];
    __shared__ int lbase[NB];
    int t = threadIdx.x;
    for (int i = t; i < NB; i += 256) lh[i] = 0;
    __syncthreads();
    int e0 = blockIdx.x * 4096;
#pragma unroll
    for (int i = 0; i < 16; i++) {
        int e = e0 + t + i * 256;
        if (e < N_EDGES) atomicAdd(&lh[dst[e] >> 9], 1);
    }
    __syncthreads();
    for (int i = t; i < NB; i += 256) {
        int c = lh[i];
        lbase[i] = c ? atomicAdd(&gcur[i], c) : 0;
        lh[i] = 0;
    }
    __syncthreads();
#pragma unroll
    for (int i = 0; i < 16; i++) {
        int e = e0 + t + i * 256;
        if (e < N_EDGES) {
            int d = dst[e];
            int b = d >> 9;
            int r = atomicAdd(&lh[b], 1);
            int2 pk;
            pk.x = ((d & 511) << 23) | (src[e] * 80 + etype[e] * 16);
            pk.y = __float_as_int(mask[e]);
            ebuf[lbase[b] + r] = pk;
        }
    }
}

// ---------------- weight prep: Wbig[d][j], j<160: rel-expanded; j>=160: loop ----------------

__global__ void k_prepw(const float* __restrict__ V, const float* __restrict__ comp,
                        const float* __restrict__ loopw, float* __restrict__ Wbig, int D) {
    int idx = blockIdx.x * 256 + threadIdx.x;
    if (idx >= D * 192) return;
    int d = idx / 192, j = idx % 192;
    float v;
    if (j < 160) {
        int r = j >> 5, o = j & 31;
        v = comp[r * 2 + 0] * V[(size_t)(0 * D + d) * 32 + o]
          + comp[r * 2 + 1] * V[(size_t)(1 * D + d) * 32 + o];
    } else {
        v = loopw[d * 32 + (j - 160)];
    }
    Wbig[idx] = v;
}

// ---------------- transform L1: 512 threads, 128-node tiles, D=128 ----------------

__global__ __launch_bounds__(512) void k_transform_big(
    const float* __restrict__ xin,
    const float* __restrict__ Wbig, const float* __restrict__ bias,
    unsigned int* __restrict__ xrel16, float* __restrict__ agg) {
    __shared__ float xs[128 * 33];    // 16.9 KB
    __shared__ float ws[32 * 192];    // 24 KB
    int t = threadIdx.x;
    int tn = t & 31, to = t >> 5;     // 32 node-threads x 16 out-groups
    int n0 = blockIdx.x * 128;
    float acc[4][12];
#pragma unroll
    for (int a = 0; a < 4; a++)
#pragma unroll
        for (int b = 0; b < 12; b++) acc[a][b] = 0.f;

    for (int kc = 0; kc < IN_FEATS; kc += 32) {
        {   // stage x tile
            int col = t & 31, rbase = t >> 5;
#pragma unroll
            for (int i = 0; i < 8; i++) {
                int row = i * 16 + rbase;
                int n = n0 + row;
                xs[row * 33 + col] = (n < N_NODES) ? xin[(size_t)n * IN_FEATS + kc + col] : 0.f;
            }
        }
        {   // stage W chunk (6144 floats)
            const float4* srcp = (const float4*)(Wbig + kc * 192);
            float4* dstp = (float4*)ws;
#pragma unroll
            for (int i = 0; i < 3; i++) dstp[t + i * 512] = srcp[t + i * 512];
        }
        __syncthreads();
#pragma unroll 8
        for (int k = 0; k < 32; k++) {
            float xf[4];
#pragma unroll
            for (int ni = 0; ni < 4; ni++) xf[ni] = xs[(tn * 4 + ni) * 33 + k];
            const float4* wr4 = (const float4*)(ws + k * 192 + to * 12);
            float4 w0 = wr4[0], w1 = wr4[1], w2 = wr4[2];
            float wf[12] = {w0.x, w0.y, w0.z, w0.w, w1.x, w1.y, w1.z, w1.w,
                            w2.x, w2.y, w2.z, w2.w};
#pragma unroll
            for (int ni = 0; ni < 4; ni++)
#pragma unroll
                for (int oi = 0; oi < 12; oi++)
                    acc[ni][oi] = fmaf(xf[ni], wf[oi], acc[ni][oi]);
        }
        __syncthreads();
    }
#pragma unroll
    for (int ni = 0; ni < 4; ni++) {
        int n = n0 + tn * 4 + ni;
        if (n >= N_NODES) continue;
#pragma unroll
        for (int oi = 0; oi < 12; oi += 2) {
            int j = to * 12 + oi;
            if (j < 160) {
                xrel16[(size_t)n * 80 + (j >> 1)] = pack_bf16(acc[ni][oi], acc[ni][oi + 1]);
            } else {
                agg[(size_t)n * 32 + (j - 160)]     = acc[ni][oi]     + bias[j - 160];
                agg[(size_t)n * 32 + (j - 160) + 1] = acc[ni][oi + 1] + bias[j - 159];
            }
        }
    }
}

// ---------------- transform L2/L3: D=32, NT tiles per block reusing staged W ----------------

#define NT_SMALL 4
__global__ __launch_bounds__(256) void k_transform_small(
    const float* __restrict__ xin, int xstride,
    const float* __restrict__ Wbig, const float* __restrict__ bias,
    unsigned int* __restrict__ xrel16, float* __restrict__ agg) {
    __shared__ float ws[32 * 192];    // 24 KB, staged once
    __shared__ float xs[64 * 33];     // 8.6 KB
    int t = threadIdx.x;
    int tn = t & 15, to = t >> 4;
    {
        const float4* srcp = (const float4*)Wbig;
        float4* dstp = (float4*)ws;
#pragma unroll
        for (int i = 0; i < 6; i++) dstp[t + i * 256] = srcp[t + i * 256];
    }
    for (int tile = 0; tile < NT_SMALL; tile++) {
        int n0 = (blockIdx.x * NT_SMALL + tile) * 64;
        __syncthreads();
        {
            int col = t & 31, rbase = t >> 5;
#pragma unroll
            for (int i = 0; i < 8; i++) {
                int row = i * 8 + rbase;
                int n = n0 + row;
                xs[row * 33 + col] = (n < N_NODES) ? xin[(size_t)n * xstride + col] : 0.f;
            }
        }
        __syncthreads();
        float acc[4][12];
#pragma unroll
        for (int a = 0; a < 4; a++)
#pragma unroll
            for (int b = 0; b < 12; b++) acc[a][b] = 0.f;
#pragma unroll 8
        for (int k = 0; k < 32; k++) {
            float xf[4];
#pragma unroll
            for (int ni = 0; ni < 4; ni++) xf[ni] = xs[(tn * 4 + ni) * 33 + k];
            const float4* wr4 = (const float4*)(ws + k * 192 + to * 12);
            float4 w0 = wr4[0], w1 = wr4[1], w2 = wr4[2];
            float wf[12] = {w0.x, w0.y, w0.z, w0.w, w1.x, w1.y, w1.z, w1.w,
                            w2.x, w2.y, w2.z, w2.w};
#pragma unroll
            for (int ni = 0; ni < 4; ni++)
#pragma unroll
                for (int oi = 0; oi < 12; oi++)
                    acc[ni][oi] = fmaf(xf[ni], wf[oi], acc[ni][oi]);
        }
#pragma unroll
        for (int ni = 0; ni < 4; ni++) {
            int n = n0 + tn * 4 + ni;
            if (n >= N_NODES) continue;
#pragma unroll
            for (int oi = 0; oi < 12; oi += 2) {
                int j = to * 12 + oi;
                if (j < 160) {
                    xrel16[(size_t)n * 80 + (j >> 1)] = pack_bf16(acc[ni][oi], acc[ni][oi + 1]);
                } else {
                    agg[(size_t)n * 32 + (j - 160)]     = acc[ni][oi]     + bias[j - 160];
                    agg[(size_t)n * 32 + (j - 160) + 1] = acc[ni][oi + 1] + bias[j - 159];
                }
            }
        }
    }
}

// ---------------- aggregation: one block per bucket, LDS fp32 accumulators ----------------

__global__ __launch_bounds__(1024) void k_agg_lds(
    const int* __restrict__ bases, const int2* __restrict__ ebuf,
    const unsigned int* __restrict__ xrel16, const float* __restrict__ agg,
    float* __restrict__ hout, int hoff) {
    __shared__ float facc[512 * 32];   // 64 KB
    int b = blockIdx.x;
    int nb = b << 9;
    int tid = threadIdx.x;
    for (int idx = tid; idx < 512 * 32; idx += 1024) {
        int n = nb + (idx >> 5);
        facc[idx] = (n < N_NODES) ? agg[(size_t)n * 32 + (idx & 31)] : 0.f;
    }
    __syncthreads();
    int s0 = bases[b], s1 = bases[b + 1];
    if (s1 > s0) {
        int g = tid >> 4, o = tid & 15;   // 64 groups of 16 lanes
        int last = s1 - 1;
        for (int e0 = s0 + g * 16; e0 < s1; e0 += 64 * 16) {
            // each lane loads record e0+o, broadcast via width-16 shuffle
            int myec = e0 + o; if (myec > last) myec = last;
            int2 mypk = ebuf[myec];
            int addr[16], dl[16]; float m[16];
#pragma unroll
            for (int i = 0; i < 16; i++) {
                int px = __shfl(mypk.x, i, 16);
                int py = __shfl(mypk.y, i, 16);
                addr[i] = px & 0x7fffff;
                dl[i]   = ((unsigned)px) >> 23;
                m[i]    = (e0 + i <= last) ? __int_as_float(py) : 0.f;
            }
            unsigned int xw[16];
#pragma unroll
            for (int i = 0; i < 16; i++) xw[i] = xrel16[(unsigned)addr[i] + o];
#pragma unroll
            for (int i = 0; i < 16; i++) {
                float lo = __uint_as_float(xw[i] << 16);
                float hi = __uint_as_float(xw[i] & 0xffff0000u);
                atomicAdd(&facc[dl[i] * 32 + 2 * o],     m[i] * lo);
                atomicAdd(&facc[dl[i] * 32 + 2 * o + 1], m[i] * hi);
            }
        }
    }
    __syncthreads();
    for (int idx = tid; idx < 512 * 32; idx += 1024) {
        int n = nb + (idx >> 5);
        if (n < N_NODES) hout[(size_t)n * 96 + hoff + (idx & 31)] = tanhf(facc[idx]);
    }
}

// ---------------- MLP head ----------------

__global__ void k_mlp(const float* __restrict__ concat, const int* __restrict__ uidx,
                      const int* __restrict__ iidx,
                      const float* __restrict__ w1, const float* __restrict__ bw1,
                      const float* __restrict__ w2, const float* __restrict__ bw2,
                      float* __restrict__ out) {
    __shared__ float feats[192];
    __shared__ float red[2];
    int p = blockIdx.x;
    int t = threadIdx.x;   // 128 threads
    int u = uidx[p], it = iidx[p];
    for (int k = t; k < 192; k += 128)
        feats[k] = (k < 96) ? concat[(size_t)u * 96 + k] : concat[(size_t)it * 96 + (k - 96)];
    __syncthreads();
    float acc = bw1[t];
    for (int k = 0; k < 192; k++) acc += feats[k] * w1[k * 128 + t];
    float h = fmaxf(acc, 0.f);
    float part = h * w2[t];
    for (int off = 32; off > 0; off >>= 1) part += __shfl_down(part, off, 64);
    if ((t & 63) == 0) red[t >> 6] = part;
    __syncthreads();
    if (t == 0) out[p] = red[0] + red[1] + bw2[0];
}

// ---------------- launch ----------------

extern "C" void kernel_launch(void* const* d_in, const int* in_sizes, int n_in,
                              void* d_out, int out_size, void* d_ws, size_t ws_size,
                              hipStream_t stream) {
    const float* x         = (const float*)d_in[0];
    const float* edge_mask = (const float*)d_in[1];
    const int*   etype     = (const int*)d_in[2];
    const int*   src       = (const int*)d_in[3];
    const int*   dst       = (const int*)d_in[4];
    const int*   users_idx = (const int*)d_in[5];
    const int*   items_idx = (const int*)d_in[6];
    const float* V1        = (const float*)d_in[7];
    const float* comp1     = (const float*)d_in[8];
    const float* loop1     = (const float*)d_in[9];
    const float* b1        = (const float*)d_in[10];
    const float* V2        = (const float*)d_in[11];
    const float* comp2     = (const float*)d_in[12];
    const float* loop2     = (const float*)d_in[13];
    const float* b2        = (const float*)d_in[14];
    const float* V3        = (const float*)d_in[15];
    const float* comp3     = (const float*)d_in[16];
    const float* loop3     = (const float*)d_in[17];
    const float* b3        = (const float*)d_in[18];
    const float* w1        = (const float*)d_in[19];
    const float* bw1       = (const float*)d_in[20];
    const float* w2        = (const float*)d_in[21];
    const float* bw2       = (const float*)d_in[22];
    float* out = (float*)d_out;

    uintptr_t w = (uintptr_t)d_ws;
    auto al = [&](size_t bytes) { uintptr_t p = (w + 255) & ~(uintptr_t)255; w = p + bytes; return p; };
    int*   ghist  = (int*)al(sizeof(int) * NB);
    int*   bases  = (int*)al(sizeof(int) * (NB + 1));
    int*   gcur   = (int*)al(sizeof(int) * NB);
    int2*  ebuf   = (int2*)al(sizeof(int2) * N_EDGES);
    float* Wbig   = (float*)al(sizeof(float) * IN_FEATS * 192);
    unsigned int* xrel16 = (unsigned int*)al(sizeof(unsigned int) * (size_t)N_NODES * 80);
    float* agg    = (float*)al(sizeof(float) * (size_t)N_NODES * 32);
    float* concat = (float*)al(sizeof(float) * (size_t)N_NODES * 96);

    hipMemsetAsync(ghist, 0, sizeof(int) * NB, stream);

    k_bcount<<<BSCAT_BLOCKS, 256, 0, stream>>>(dst, ghist);
    k_bscan<<<1, 256, 0, stream>>>(ghist, bases, gcur);
    k_bscatter<<<BSCAT_BLOCKS, 256, 0, stream>>>(src, dst, etype, edge_mask, gcur, ebuf);

    // layer 1
    k_prepw<<<(IN_FEATS * 192 + 255) / 256, 256, 0, stream>>>(V1, comp1, loop1, Wbig, IN_FEATS);
    k_transform_big<<<(N_NODES + 127) / 128, 512, 0, stream>>>(x, Wbig, b1, xrel16, agg);
    k_agg_lds<<<NB, 1024, 0, stream>>>(bases, ebuf, xrel16, agg, concat + 0, 0);

    // layer 2
    k_prepw<<<(HID * 192 + 255) / 256, 256, 0, stream>>>(V2, comp2, loop2, Wbig, HID);
    k_transform_small<<<(N_NODES + NT_SMALL * 64 - 1) / (NT_SMALL * 64), 256, 0, stream>>>(
        concat + 0, 96, Wbig, b2, xrel16, agg);
    k_agg_lds<<<NB, 1024, 0, stream>>>(bases, ebuf, xrel16, agg, concat + 0, 32);

    // layer 3
    k_prepw<<<(HID * 192 + 255) / 256, 256, 0, stream>>>(V3, comp3, loop3, Wbig, HID);
    k_transform_small<<<(N_NODES + NT_SMALL * 64 - 1) / (NT_SMALL * 64), 256, 0, stream>>>(
        concat + 32, 96, Wbig, b3, xrel16, agg);
    k_agg_lds<<<NB, 1024, 0, stream>>>(bases, ebuf, xrel16, agg, concat + 0, 64);

    k_mlp<<<N_PAIRS, 128, 0, stream>>>(concat, users_idx, items_idx, w1, bw1, w2, bw2, out);
}

// Round 5
// 569.767 us; speedup vs baseline: 2.6302x; 2.6302x over previous
//
#include <hip/hip_runtime.h>
#include <stdint.h>

#define N_NODES  100000
#define N_EDGES  1600000
#define IN_FEATS 128
#define HID      32
#define N_REL    5
#define N_BASES  2
#define N_PAIRS  4096

#define NB        196        // buckets of 512 dst nodes
#define BSCAT_BLOCKS 391     // ceil(1600000/4096)

__device__ inline unsigned int pack_bf16(float a, float b) {
    unsigned int ua = __float_as_uint(a), ub = __float_as_uint(b);
    ua = (ua + 0x7fffu + ((ua >> 16) & 1u)) >> 16;
    ub = (ub + 0x7fffu + ((ub >> 16) & 1u)) >> 16;
    return ua | (ub << 16);
}

// ---------------- bucket histogram / scan / scatter ----------------

__global__ __launch_bounds__(256) void k_bcount(const int* __restrict__ dst,
                                                int* __restrict__ ghist) {
    __shared__ int lh[NB];
    int t = threadIdx.x;
    for (int i = t; i < NB; i += 256) lh[i] = 0;
    __syncthreads();
    int e0 = blockIdx.x * 4096;
#pragma unroll
    for (int i = 0; i < 16; i++) {
        int e = e0 + t + i * 256;
        if (e < N_EDGES) atomicAdd(&lh[dst[e] >> 9], 1);
    }
    __syncthreads();
    for (int i = t; i < NB; i += 256) {
        int c = lh[i];
        if (c) atomicAdd(&ghist[i], c);
    }
}

__global__ void k_bscan(const int* __restrict__ ghist, int* __restrict__ bases,
                        int* __restrict__ gcur) {
    __shared__ int s[256];
    int t = threadIdx.x;
    int v = (t < NB) ? ghist[t] : 0;
    s[t] = v;
    __syncthreads();
    for (int off = 1; off < 256; off <<= 1) {
        int u = (t >= off) ? s[t - off] : 0;
        __syncthreads();
        s[t] += u;
        __syncthreads();
    }
    if (t < NB) {
        int excl = s[t] - v;
        bases[t] = excl;
        gcur[t]  = excl;
    }
    if (t == 0) bases[NB] = N_EDGES;
}

// record: x = (dst&511)<<23 | (src*80 + etype*16), y = mask fp32
__global__ __launch_bounds__(256) void k_bscatter(
    const int* __restrict__ src, const int* __restrict__ dst,
    const int* __restrict__ etype, const float* __restrict__ mask,
    int* __restrict__ gcur, int2* __restrict__ ebuf) {
    __shared__ int lh[NB];
    __shared__ int lbase[NB];
    int t = threadIdx.x;
    for (int i = t; i < NB; i += 256) lh[i] = 0;
    __syncthreads();
    int e0 = blockIdx.x * 4096;
#pragma unroll
    for (int i = 0; i < 16; i++) {
        int e = e0 + t + i * 256;
        if (e < N_EDGES) atomicAdd(&lh[dst[e] >> 9], 1);
    }
    __syncthreads();
    for (int i = t; i < NB; i += 256) {
        int c = lh[i];
        lbase[i] = c ? atomicAdd(&gcur[i], c) : 0;
        lh[i] = 0;
    }
    __syncthreads();
#pragma unroll
    for (int i = 0; i < 16; i++) {
        int e = e0 + t + i * 256;
        if (e < N_EDGES) {
            int d = dst[e];
            int b = d >> 9;
            int r = atomicAdd(&lh[b], 1);
            int2 pk;
            pk.x = ((d & 511) << 23) | (src[e] * 80 + etype[e] * 16);
            pk.y = __float_as_int(mask[e]);
            ebuf[lbase[b] + r] = pk;
        }
    }
}

// ---------------- per-bucket counting sort -> full CSR (esort + offsets) ----------------

__global__ __launch_bounds__(1024) void k_bsort(
    const int* __restrict__ bases, const int2* __restrict__ ebuf,
    int2* __restrict__ esort, int* __restrict__ offsets) {
    __shared__ int hist[512];
    __shared__ int incl[512];
    __shared__ int cur[512];
    int b = blockIdx.x, t = threadIdx.x;
    int s0 = bases[b], s1 = bases[b + 1];
    if (t < 512) hist[t] = 0;
    __syncthreads();
    for (int e = s0 + t; e < s1; e += 1024) {
        int dl = ((unsigned)ebuf[e].x) >> 23;
        atomicAdd(&hist[dl], 1);
    }
    __syncthreads();
    if (t < 512) incl[t] = hist[t];
    __syncthreads();
    for (int off = 1; off < 512; off <<= 1) {
        int v = 0;
        if (t < 512 && t >= off) v = incl[t - off];
        __syncthreads();
        if (t < 512) incl[t] += v;
        __syncthreads();
    }
    if (t < 512) {
        int ex = incl[t] - hist[t];
        cur[t] = ex;
        int n = (b << 9) + t;
        if (n <= N_NODES) offsets[n] = s0 + ex;
    }
    __syncthreads();
    for (int e = s0 + t; e < s1; e += 1024) {
        int2 pk = ebuf[e];
        int dl = ((unsigned)pk.x) >> 23;
        int pos = s0 + atomicAdd(&cur[dl], 1);
        int2 rec;
        rec.x = pk.x & 0x7fffff;
        rec.y = pk.y;
        esort[pos] = rec;
    }
}

// ---------------- weight prep: Wbig[d][j], j<160: rel-expanded; j>=160: loop ----------------

__global__ void k_prepw(const float* __restrict__ V, const float* __restrict__ comp,
                        const float* __restrict__ loopw, float* __restrict__ Wbig, int D) {
    int idx = blockIdx.x * 256 + threadIdx.x;
    if (idx >= D * 192) return;
    int d = idx / 192, j = idx % 192;
    float v;
    if (j < 160) {
        int r = j >> 5, o = j & 31;
        v = comp[r * 2 + 0] * V[(size_t)(0 * D + d) * 32 + o]
          + comp[r * 2 + 1] * V[(size_t)(1 * D + d) * 32 + o];
    } else {
        v = loopw[d * 32 + (j - 160)];
    }
    Wbig[idx] = v;
}

// ---------------- transform L1: 512 thr, 128-node tiles, transposed xs + reg prefetch ----------------

__global__ __launch_bounds__(512) void k_transform_big(
    const float* __restrict__ xin,
    const float* __restrict__ Wbig, const float* __restrict__ bias,
    unsigned int* __restrict__ xrel16, float* __restrict__ agg) {
    __shared__ float xs[32 * 132];    // [k][n], stride 132 (b128-aligned reads)
    __shared__ float ws[32 * 192];    // [k][j]
    int t = threadIdx.x;
    int tn = t & 31, to = t >> 5;     // 32 node-threads x 16 out-groups
    int col = t & 31, rbase = t >> 5; // staging role: col = k, rows
    int n0 = blockIdx.x * 128;
    float acc[4][12];
#pragma unroll
    for (int a = 0; a < 4; a++)
#pragma unroll
        for (int b = 0; b < 12; b++) acc[a][b] = 0.f;

    float xpre[8];
    float4 wpre[3];
    {   // prefetch chunk 0
#pragma unroll
        for (int i = 0; i < 8; i++) {
            int n = n0 + rbase + i * 16;
            xpre[i] = (n < N_NODES) ? xin[(size_t)n * IN_FEATS + col] : 0.f;
        }
        const float4* wsrc = (const float4*)Wbig;
#pragma unroll
        for (int i = 0; i < 3; i++) wpre[i] = wsrc[t + i * 512];
    }

    for (int kc = 0; kc < IN_FEATS; kc += 32) {
        // commit prefetched regs to LDS
#pragma unroll
        for (int i = 0; i < 8; i++) xs[col * 132 + rbase + i * 16] = xpre[i];
        {
            float4* wdst = (float4*)ws;
#pragma unroll
            for (int i = 0; i < 3; i++) wdst[t + i * 512] = wpre[i];
        }
        __syncthreads();
        if (kc + 32 < IN_FEATS) {   // prefetch next chunk during compute
            int kn = kc + 32;
#pragma unroll
            for (int i = 0; i < 8; i++) {
                int n = n0 + rbase + i * 16;
                xpre[i] = (n < N_NODES) ? xin[(size_t)n * IN_FEATS + kn + col] : 0.f;
            }
            const float4* wsrc = (const float4*)(Wbig + kn * 192);
#pragma unroll
            for (int i = 0; i < 3; i++) wpre[i] = wsrc[t + i * 512];
        }
#pragma unroll 8
        for (int k = 0; k < 32; k++) {
            float4 xv = *(const float4*)(xs + k * 132 + tn * 4);
            float xf[4] = {xv.x, xv.y, xv.z, xv.w};
            const float4* wr4 = (const float4*)(ws + k * 192 + to * 12);
            float4 w0 = wr4[0], w1 = wr4[1], w2 = wr4[2];
            float wf[12] = {w0.x, w0.y, w0.z, w0.w, w1.x, w1.y, w1.z, w1.w,
                            w2.x, w2.y, w2.z, w2.w};
#pragma unroll
            for (int ni = 0; ni < 4; ni++)
#pragma unroll
                for (int oi = 0; oi < 12; oi++)
                    acc[ni][oi] = fmaf(xf[ni], wf[oi], acc[ni][oi]);
        }
        __syncthreads();
    }
#pragma unroll
    for (int ni = 0; ni < 4; ni++) {
        int n = n0 + tn * 4 + ni;
        if (n >= N_NODES) continue;
#pragma unroll
        for (int oi = 0; oi < 12; oi += 2) {
            int j = to * 12 + oi;
            if (j < 160) {
                xrel16[(size_t)n * 80 + (j >> 1)] = pack_bf16(acc[ni][oi], acc[ni][oi + 1]);
            } else {
                agg[(size_t)n * 32 + (j - 160)]     = acc[ni][oi]     + bias[j - 160];
                agg[(size_t)n * 32 + (j - 160) + 1] = acc[ni][oi + 1] + bias[j - 159];
            }
        }
    }
}

// ---------------- transform L2/L3: D=32, 4 tiles/block, W staged once, transposed xs ----------------

#define NT_SMALL 4
__global__ __launch_bounds__(256) void k_transform_small(
    const float* __restrict__ xin, int xstride,
    const float* __restrict__ Wbig, const float* __restrict__ bias,
    unsigned int* __restrict__ xrel16, float* __restrict__ agg) {
    __shared__ float ws[32 * 192];    // 24 KB, staged once
    __shared__ float xs[32 * 68];     // [k][n], 64 nodes
    int t = threadIdx.x;
    int tn = t & 15, to = t >> 4;
    {
        const float4* srcp = (const float4*)Wbig;
        float4* dstp = (float4*)ws;
#pragma unroll
        for (int i = 0; i < 6; i++) dstp[t + i * 256] = srcp[t + i * 256];
    }
    for (int tile = 0; tile < NT_SMALL; tile++) {
        int n0 = (blockIdx.x * NT_SMALL + tile) * 64;
        __syncthreads();
        {
            int col = t & 31, row = t >> 5;
#pragma unroll
            for (int i = 0; i < 8; i++) {
                int r = row + i * 8;
                int n = n0 + r;
                xs[col * 68 + r] = (n < N_NODES) ? xin[(size_t)n * xstride + col] : 0.f;
            }
        }
        __syncthreads();
        float acc[4][12];
#pragma unroll
        for (int a = 0; a < 4; a++)
#pragma unroll
            for (int b = 0; b < 12; b++) acc[a][b] = 0.f;
#pragma unroll 8
        for (int k = 0; k < 32; k++) {
            float4 xv = *(const float4*)(xs + k * 68 + tn * 4);
            float xf[4] = {xv.x, xv.y, xv.z, xv.w};
            const float4* wr4 = (const float4*)(ws + k * 192 + to * 12);
            float4 w0 = wr4[0], w1 = wr4[1], w2 = wr4[2];
            float wf[12] = {w0.x, w0.y, w0.z, w0.w, w1.x, w1.y, w1.z, w1.w,
                            w2.x, w2.y, w2.z, w2.w};
#pragma unroll
            for (int ni = 0; ni < 4; ni++)
#pragma unroll
                for (int oi = 0; oi < 12; oi++)
                    acc[ni][oi] = fmaf(xf[ni], wf[oi], acc[ni][oi]);
        }
#pragma unroll
        for (int ni = 0; ni < 4; ni++) {
            int n = n0 + tn * 4 + ni;
            if (n >= N_NODES) continue;
#pragma unroll
            for (int oi = 0; oi < 12; oi += 2) {
                int j = to * 12 + oi;
                if (j < 160) {
                    xrel16[(size_t)n * 80 + (j >> 1)] = pack_bf16(acc[ni][oi], acc[ni][oi + 1]);
                } else {
                    agg[(size_t)n * 32 + (j - 160)]     = acc[ni][oi]     + bias[j - 160];
                    agg[(size_t)n * 32 + (j - 160) + 1] = acc[ni][oi + 1] + bias[j - 159];
                }
            }
        }
    }
}

// ---------------- aggregation: 8 lanes/node, uint2 gathers, 8-deep, reg accumulate ----------------

__global__ __launch_bounds__(256) void k_agg(
    const int* __restrict__ offsets, const int2* __restrict__ esort,
    const unsigned int* __restrict__ xrel16, const float* __restrict__ agg,
    float* __restrict__ hout, int hoff) {
    int v = blockIdx.x * 32 + (threadIdx.x >> 3);
    int o = threadIdx.x & 7;
    if (v >= N_NODES) return;
    int s0 = offsets[v], s1 = offsets[v + 1];
    float4 a0 = *(const float4*)(agg + (size_t)v * 32 + o * 4);
    float acc0 = a0.x, acc1 = a0.y, acc2 = a0.z, acc3 = a0.w;
    int last = s1 - 1;
    for (int e = s0; e < s1; e += 8) {
        int addr[8];
        float m[8];
#pragma unroll
        for (int i = 0; i < 8; i++) {
            int ei = e + i;
            int ec = (ei <= last) ? ei : last;
            int2 pk = esort[ec];
            addr[i] = pk.x;
            m[i] = (ei <= last) ? __int_as_float(pk.y) : 0.f;
        }
        uint2 xw[8];
#pragma unroll
        for (int i = 0; i < 8; i++)
            xw[i] = *(const uint2*)(xrel16 + (unsigned)addr[i] + o * 2);
#pragma unroll
        for (int i = 0; i < 8; i++) {
            float f0 = __uint_as_float(xw[i].x << 16);
            float f1 = __uint_as_float(xw[i].x & 0xffff0000u);
            float f2 = __uint_as_float(xw[i].y << 16);
            float f3 = __uint_as_float(xw[i].y & 0xffff0000u);
            acc0 = fmaf(m[i], f0, acc0);
            acc1 = fmaf(m[i], f1, acc1);
            acc2 = fmaf(m[i], f2, acc2);
            acc3 = fmaf(m[i], f3, acc3);
        }
    }
    float4 r;
    r.x = tanhf(acc0); r.y = tanhf(acc1); r.z = tanhf(acc2); r.w = tanhf(acc3);
    *(float4*)(hout + (size_t)v * 96 + hoff + o * 4) = r;
}

// ---------------- MLP head ----------------

__global__ void k_mlp(const float* __restrict__ concat, const int* __restrict__ uidx,
                      const int* __restrict__ iidx,
                      const float* __restrict__ w1, const float* __restrict__ bw1,
                      const float* __restrict__ w2, const float* __restrict__ bw2,
                      float* __restrict__ out) {
    __shared__ float feats[192];
    __shared__ float red[2];
    int p = blockIdx.x;
    int t = threadIdx.x;   // 128 threads
    int u = uidx[p], it = iidx[p];
    for (int k = t; k < 192; k += 128)
        feats[k] = (k < 96) ? concat[(size_t)u * 96 + k] : concat[(size_t)it * 96 + (k - 96)];
    __syncthreads();
    float acc = bw1[t];
    for (int k = 0; k < 192; k++) acc += feats[k] * w1[k * 128 + t];
    float h = fmaxf(acc, 0.f);
    float part = h * w2[t];
    for (int off = 32; off > 0; off >>= 1) part += __shfl_down(part, off, 64);
    if ((t & 63) == 0) red[t >> 6] = part;
    __syncthreads();
    if (t == 0) out[p] = red[0] + red[1] + bw2[0];
}

// ---------------- launch ----------------

extern "C" void kernel_launch(void* const* d_in, const int* in_sizes, int n_in,
                              void* d_out, int out_size, void* d_ws, size_t ws_size,
                              hipStream_t stream) {
    const float* x         = (const float*)d_in[0];
    const float* edge_mask = (const float*)d_in[1];
    const int*   etype     = (const int*)d_in[2];
    const int*   src       = (const int*)d_in[3];
    const int*   dst       = (const int*)d_in[4];
    const int*   users_idx = (const int*)d_in[5];
    const int*   items_idx = (const int*)d_in[6];
    const float* V1        = (const float*)d_in[7];
    const float* comp1     = (const float*)d_in[8];
    const float* loop1     = (const float*)d_in[9];
    const float* b1        = (const float*)d_in[10];
    const float* V2        = (const float*)d_in[11];
    const float* comp2     = (const float*)d_in[12];
    const float* loop2     = (const float*)d_in[13];
    const float* b2        = (const float*)d_in[14];
    const float* V3        = (const float*)d_in[15];
    const float* comp3     = (const float*)d_in[16];
    const float* loop3     = (const float*)d_in[17];
    const float* b3        = (const float*)d_in[18];
    const float* w1        = (const float*)d_in[19];
    const float* bw1       = (const float*)d_in[20];
    const float* w2        = (const float*)d_in[21];
    const float* bw2       = (const float*)d_in[22];
    float* out = (float*)d_out;

    uintptr_t w = (uintptr_t)d_ws;
    auto al = [&](size_t bytes) { uintptr_t p = (w + 255) & ~(uintptr_t)255; w = p + bytes; return p; };
    int*   ghist   = (int*)al(sizeof(int) * NB);
    int*   bases   = (int*)al(sizeof(int) * (NB + 1));
    int*   gcur    = (int*)al(sizeof(int) * NB);
    int*   offsets = (int*)al(sizeof(int) * (N_NODES + 1));
    // ebuf (12.8 MB) is dead after k_bsort; xrel16 (32 MB) aliases it.
    uintptr_t big0 = al(sizeof(unsigned int) * (size_t)N_NODES * 80);
    int2*  ebuf    = (int2*)big0;
    unsigned int* xrel16 = (unsigned int*)big0;
    int2*  esort   = (int2*)al(sizeof(int2) * N_EDGES);
    float* Wbig    = (float*)al(sizeof(float) * IN_FEATS * 192);
    float* agg     = (float*)al(sizeof(float) * (size_t)N_NODES * 32);
    float* concat  = (float*)al(sizeof(float) * (size_t)N_NODES * 96);

    hipMemsetAsync(ghist, 0, sizeof(int) * NB, stream);

    k_bcount<<<BSCAT_BLOCKS, 256, 0, stream>>>(dst, ghist);
    k_bscan<<<1, 256, 0, stream>>>(ghist, bases, gcur);
    k_bscatter<<<BSCAT_BLOCKS, 256, 0, stream>>>(src, dst, etype, edge_mask, gcur, ebuf);
    k_bsort<<<NB, 1024, 0, stream>>>(bases, ebuf, esort, offsets);

    const int agrid = (N_NODES + 31) / 32;

    // layer 1
    k_prepw<<<(IN_FEATS * 192 + 255) / 256, 256, 0, stream>>>(V1, comp1, loop1, Wbig, IN_FEATS);
    k_transform_big<<<(N_NODES + 127) / 128, 512, 0, stream>>>(x, Wbig, b1, xrel16, agg);
    k_agg<<<agrid, 256, 0, stream>>>(offsets, esort, xrel16, agg, concat, 0);

    // layer 2
    k_prepw<<<(HID * 192 + 255) / 256, 256, 0, stream>>>(V2, comp2, loop2, Wbig, HID);
    k_transform_small<<<(N_NODES + NT_SMALL * 64 - 1) / (NT_SMALL * 64), 256, 0, stream>>>(
        concat + 0, 96, Wbig, b2, xrel16, agg);
    k_agg<<<agrid, 256, 0, stream>>>(offsets, esort, xrel16, agg, concat, 32);

    // layer 3
    k_prepw<<<(HID * 192 + 255) / 256, 256, 0, stream>>>(V3, comp3, loop3, Wbig, HID);
    k_transform_small<<<(N_NODES + NT_SMALL * 64 - 1) / (NT_SMALL * 64), 256, 0, stream>>>(
        concat + 32, 96, Wbig, b3, xrel16, agg);
    k_agg<<<agrid, 256, 0, stream>>>(offsets, esort, xrel16, agg, concat, 64);

    k_mlp<<<N_PAIRS, 128, 0, stream>>>(concat, users_idx, items_idx, w1, bw1, w2, bw2, out);
}

// Round 6
// 399.042 us; speedup vs baseline: 3.7555x; 1.4278x over previous
//
#include <hip/hip_runtime.h>
#include <stdint.h>

#define N_NODES  100000
#define N_EDGES  1600000
#define IN_FEATS 128
#define HID      32
#define N_REL    5
#define N_BASES  2
#define N_PAIRS  4096

#define NB        196        // buckets of 512 dst nodes
#define BSCAT_BLOCKS 391     // ceil(1600000/4096)

typedef __attribute__((ext_vector_type(8))) short short8;
typedef __attribute__((ext_vector_type(4))) float f32x4;

__device__ inline unsigned int pack_bf16(float a, float b) {
    unsigned int ua = __float_as_uint(a), ub = __float_as_uint(b);
    ua = (ua + 0x7fffu + ((ua >> 16) & 1u)) >> 16;
    ub = (ub + 0x7fffu + ((ub >> 16) & 1u)) >> 16;
    return ua | (ub << 16);
}

// ---------------- bucket histogram / scan / scatter ----------------

__global__ __launch_bounds__(256) void k_bcount(const int* __restrict__ dst,
                                                int* __restrict__ ghist) {
    __shared__ int lh[NB];
    int t = threadIdx.x;
    for (int i = t; i < NB; i += 256) lh[i] = 0;
    __syncthreads();
    int e0 = blockIdx.x * 4096;
#pragma unroll
    for (int i = 0; i < 16; i++) {
        int e = e0 + t + i * 256;
        if (e < N_EDGES) atomicAdd(&lh[dst[e] >> 9], 1);
    }
    __syncthreads();
    for (int i = t; i < NB; i += 256) {
        int c = lh[i];
        if (c) atomicAdd(&ghist[i], c);
    }
}

__global__ void k_bscan(const int* __restrict__ ghist, int* __restrict__ bases,
                        int* __restrict__ gcur) {
    __shared__ int s[256];
    int t = threadIdx.x;
    int v = (t < NB) ? ghist[t] : 0;
    s[t] = v;
    __syncthreads();
    for (int off = 1; off < 256; off <<= 1) {
        int u = (t >= off) ? s[t - off] : 0;
        __syncthreads();
        s[t] += u;
        __syncthreads();
    }
    if (t < NB) {
        int excl = s[t] - v;
        bases[t] = excl;
        gcur[t]  = excl;
    }
    if (t == 0) bases[NB] = N_EDGES;
}

// record: x = (dst&511)<<23 | (src*80 + etype*16), y = mask fp32
__global__ __launch_bounds__(256) void k_bscatter(
    const int* __restrict__ src, const int* __restrict__ dst,
    const int* __restrict__ etype, const float* __restrict__ mask,
    int* __restrict__ gcur, int2* __restrict__ ebuf) {
    __shared__ int lh[NB];
    __shared__ int lbase[NB];
    int t = threadIdx.x;
    for (int i = t; i < NB; i += 256) lh[i] = 0;
    __syncthreads();
    int e0 = blockIdx.x * 4096;
#pragma unroll
    for (int i = 0; i < 16; i++) {
        int e = e0 + t + i * 256;
        if (e < N_EDGES) atomicAdd(&lh[dst[e] >> 9], 1);
    }
    __syncthreads();
    for (int i = t; i < NB; i += 256) {
        int c = lh[i];
        lbase[i] = c ? atomicAdd(&gcur[i], c) : 0;
        lh[i] = 0;
    }
    __syncthreads();
#pragma unroll
    for (int i = 0; i < 16; i++) {
        int e = e0 + t + i * 256;
        if (e < N_EDGES) {
            int d = dst[e];
            int b = d >> 9;
            int r = atomicAdd(&lh[b], 1);
            int2 pk;
            pk.x = ((d & 511) << 23) | (src[e] * 80 + etype[e] * 16);
            pk.y = __float_as_int(mask[e]);
            ebuf[lbase[b] + r] = pk;
        }
    }
}

// ---------------- per-bucket counting sort -> full CSR (esort + offsets) ----------------

__global__ __launch_bounds__(1024) void k_bsort(
    const int* __restrict__ bases, const int2* __restrict__ ebuf,
    int2* __restrict__ esort, int* __restrict__ offsets) {
    __shared__ int hist[512];
    __shared__ int incl[512];
    __shared__ int cur[512];
    int b = blockIdx.x, t = threadIdx.x;
    int s0 = bases[b], s1 = bases[b + 1];
    if (t < 512) hist[t] = 0;
    __syncthreads();
    for (int e = s0 + t; e < s1; e += 1024) {
        int dl = ((unsigned)ebuf[e].x) >> 23;
        atomicAdd(&hist[dl], 1);
    }
    __syncthreads();
    if (t < 512) incl[t] = hist[t];
    __syncthreads();
    for (int off = 1; off < 512; off <<= 1) {
        int v = 0;
        if (t < 512 && t >= off) v = incl[t - off];
        __syncthreads();
        if (t < 512) incl[t] += v;
        __syncthreads();
    }
    if (t < 512) {
        int ex = incl[t] - hist[t];
        cur[t] = ex;
        int n = (b << 9) + t;
        if (n <= N_NODES) offsets[n] = s0 + ex;
    }
    __syncthreads();
    for (int e = s0 + t; e < s1; e += 1024) {
        int2 pk = ebuf[e];
        int dl = ((unsigned)pk.x) >> 23;
        int pos = s0 + atomicAdd(&cur[dl], 1);
        int2 rec;
        rec.x = pk.x & 0x7fffff;
        rec.y = pk.y;
        esort[pos] = rec;
    }
}

// ---------------- weight prep: Wbf[j][k] bf16, j<160: rel-expanded; j>=160: loop ----------------

__global__ void k_prepw_bf(const float* __restrict__ V, const float* __restrict__ comp,
                           const float* __restrict__ loopw, unsigned short* __restrict__ Wbf,
                           int D) {
    int idx = blockIdx.x * 256 + threadIdx.x;
    if (idx >= 192 * D) return;
    int j = idx / D, k = idx % D;
    float v;
    if (j < 160) {
        int r = j >> 5, o = j & 31;
        v = comp[r * 2 + 0] * V[(size_t)(0 * D + k) * 32 + o]
          + comp[r * 2 + 1] * V[(size_t)(1 * D + k) * 32 + o];
    } else {
        v = loopw[k * 32 + (j - 160)];
    }
    unsigned int u = __float_as_uint(v);
    u = (u + 0x7fffu + ((u >> 16) & 1u)) >> 16;
    Wbf[idx] = (unsigned short)u;
}

// ---------------- MFMA transform: [N,D]@[D,192] -> xrel16[N,80] bf16x2, agg[N,32] ----------------
// W' (bf16, [j][k]) staged once in LDS (stride D+8 shorts: 16B-aligned, conflict-free
// B-fragment reads). One barrier; waves then stream 16-node groups independently.

template <int D>
__global__ __launch_bounds__(256) void k_transform_mfma(
    const float* __restrict__ xin, int xstride,
    const unsigned short* __restrict__ Wbf, const float* __restrict__ bias,
    unsigned int* __restrict__ xrel16, float* __restrict__ aggout) {
    constexpr int KS = D / 32;
    constexpr int LSTR = D + 8;
    __shared__ unsigned short lw[192 * LSTR];
    int t = threadIdx.x;
    {   // stage W': global [row*D + seg*8] -> LDS [row*LSTR + seg*8], uint4 chunks
        const uint4* src = (const uint4*)Wbf;
        for (int idx = t; idx < 192 * (D / 8); idx += 256) {
            int row = idx / (D / 8), seg = idx % (D / 8);
            uint4 v = src[idx];
            *(uint4*)(lw + row * LSTR + seg * 8) = v;
        }
    }
    __syncthreads();
    int wv = t >> 6, lane = t & 63;
    int q = lane >> 4, n16 = lane & 15;
    bool even = (n16 & 1) == 0;
    int gstep = gridDim.x * 4;
    for (int g = blockIdx.x * 4 + wv; g < N_NODES / 16; g += gstep) {
        int n0 = g * 16;
        const float* xr = xin + (size_t)(n0 + n16) * xstride + q * 8;
        short8 afr[KS];
#pragma unroll
        for (int ks = 0; ks < KS; ks++) {
            float4 x0 = *(const float4*)(xr + ks * 32);
            float4 x1 = *(const float4*)(xr + ks * 32 + 4);
            union { unsigned int u[4]; short8 s; } cv;
            cv.u[0] = pack_bf16(x0.x, x0.y);
            cv.u[1] = pack_bf16(x0.z, x0.w);
            cv.u[2] = pack_bf16(x1.x, x1.y);
            cv.u[3] = pack_bf16(x1.z, x1.w);
            afr[ks] = cv.s;
        }
        f32x4 d[12];
        f32x4 z = {0.f, 0.f, 0.f, 0.f};
#pragma unroll
        for (int i = 0; i < 12; i++) d[i] = z;
#pragma unroll
        for (int t12 = 0; t12 < 12; t12++) {
#pragma unroll
            for (int ks = 0; ks < KS; ks++) {
                short8 bfr = *(const short8*)(lw + (t12 * 16 + n16) * LSTR + ks * 32 + q * 8);
                d[t12] = __builtin_amdgcn_mfma_f32_16x16x32_bf16(afr[ks], bfr, d[t12], 0, 0, 0);
            }
        }
        // epilogue: lane holds D[m=q*4+r][n=n16] for out col j = t12*16+n16
#pragma unroll
        for (int t12 = 0; t12 < 10; t12++) {
#pragma unroll
            for (int r = 0; r < 4; r++) {
                float own = d[t12][r];
                float oth = __shfl_xor(own, 1, 64);
                if (even) {
                    unsigned int pk = pack_bf16(own, oth);
                    int node = n0 + q * 4 + r;
                    xrel16[(size_t)node * 80 + (t12 * 16 + n16) / 2] = pk;
                }
            }
        }
#pragma unroll
        for (int t12 = 10; t12 < 12; t12++) {
            int o = (t12 - 10) * 16 + n16;
            float bv = bias[o];
#pragma unroll
            for (int r = 0; r < 4; r++) {
                int node = n0 + q * 4 + r;
                aggout[(size_t)node * 32 + o] = d[t12][r] + bv;
            }
        }
    }
}

// ---------------- aggregation: 8 lanes/node, uint2 gathers, 8-deep, reg accumulate ----------------

__global__ __launch_bounds__(256) void k_agg(
    const int* __restrict__ offsets, const int2* __restrict__ esort,
    const unsigned int* __restrict__ xrel16, const float* __restrict__ agg,
    float* __restrict__ hout, int hoff) {
    int v = blockIdx.x * 32 + (threadIdx.x >> 3);
    int o = threadIdx.x & 7;
    if (v >= N_NODES) return;
    int s0 = offsets[v], s1 = offsets[v + 1];
    float4 a0 = *(const float4*)(agg + (size_t)v * 32 + o * 4);
    float acc0 = a0.x, acc1 = a0.y, acc2 = a0.z, acc3 = a0.w;
    int last = s1 - 1;
    for (int e = s0; e < s1; e += 8) {
        int addr[8];
        float m[8];
#pragma unroll
        for (int i = 0; i < 8; i++) {
            int ei = e + i;
            int ec = (ei <= last) ? ei : last;
            int2 pk = esort[ec];
            addr[i] = pk.x;
            m[i] = (ei <= last) ? __int_as_float(pk.y) : 0.f;
        }
        uint2 xw[8];
#pragma unroll
        for (int i = 0; i < 8; i++)
            xw[i] = *(const uint2*)(xrel16 + (unsigned)addr[i] + o * 2);
#pragma unroll
        for (int i = 0; i < 8; i++) {
            float f0 = __uint_as_float(xw[i].x << 16);
            float f1 = __uint_as_float(xw[i].x & 0xffff0000u);
            float f2 = __uint_as_float(xw[i].y << 16);
            float f3 = __uint_as_float(xw[i].y & 0xffff0000u);
            acc0 = fmaf(m[i], f0, acc0);
            acc1 = fmaf(m[i], f1, acc1);
            acc2 = fmaf(m[i], f2, acc2);
            acc3 = fmaf(m[i], f3, acc3);
        }
    }
    float4 r;
    r.x = tanhf(acc0); r.y = tanhf(acc1); r.z = tanhf(acc2); r.w = tanhf(acc3);
    *(float4*)(hout + (size_t)v * 96 + hoff + o * 4) = r;
}

// ---------------- MLP head ----------------

__global__ void k_mlp(const float* __restrict__ concat, const int* __restrict__ uidx,
                      const int* __restrict__ iidx,
                      const float* __restrict__ w1, const float* __restrict__ bw1,
                      const float* __restrict__ w2, const float* __restrict__ bw2,
                      float* __restrict__ out) {
    __shared__ float feats[192];
    __shared__ float red[2];
    int p = blockIdx.x;
    int t = threadIdx.x;   // 128 threads
    int u = uidx[p], it = iidx[p];
    for (int k = t; k < 192; k += 128)
        feats[k] = (k < 96) ? concat[(size_t)u * 96 + k] : concat[(size_t)it * 96 + (k - 96)];
    __syncthreads();
    float acc = bw1[t];
    for (int k = 0; k < 192; k++) acc += feats[k] * w1[k * 128 + t];
    float h = fmaxf(acc, 0.f);
    float part = h * w2[t];
    for (int off = 32; off > 0; off >>= 1) part += __shfl_down(part, off, 64);
    if ((t & 63) == 0) red[t >> 6] = part;
    __syncthreads();
    if (t == 0) out[p] = red[0] + red[1] + bw2[0];
}

// ---------------- launch ----------------

extern "C" void kernel_launch(void* const* d_in, const int* in_sizes, int n_in,
                              void* d_out, int out_size, void* d_ws, size_t ws_size,
                              hipStream_t stream) {
    const float* x         = (const float*)d_in[0];
    const float* edge_mask = (const float*)d_in[1];
    const int*   etype     = (const int*)d_in[2];
    const int*   src       = (const int*)d_in[3];
    const int*   dst       = (const int*)d_in[4];
    const int*   users_idx = (const int*)d_in[5];
    const int*   items_idx = (const int*)d_in[6];
    const float* V1        = (const float*)d_in[7];
    const float* comp1     = (const float*)d_in[8];
    const float* loop1     = (const float*)d_in[9];
    const float* b1        = (const float*)d_in[10];
    const float* V2        = (const float*)d_in[11];
    const float* comp2     = (const float*)d_in[12];
    const float* loop2     = (const float*)d_in[13];
    const float* b2        = (const float*)d_in[14];
    const float* V3        = (const float*)d_in[15];
    const float* comp3     = (const float*)d_in[16];
    const float* loop3     = (const float*)d_in[17];
    const float* b3        = (const float*)d_in[18];
    const float* w1        = (const float*)d_in[19];
    const float* bw1       = (const float*)d_in[20];
    const float* w2        = (const float*)d_in[21];
    const float* bw2       = (const float*)d_in[22];
    float* out = (float*)d_out;

    uintptr_t w = (uintptr_t)d_ws;
    auto al = [&](size_t bytes) { uintptr_t p = (w + 255) & ~(uintptr_t)255; w = p + bytes; return p; };
    int*   ghist   = (int*)al(sizeof(int) * NB);
    int*   bases   = (int*)al(sizeof(int) * (NB + 1));
    int*   gcur    = (int*)al(sizeof(int) * NB);
    int*   offsets = (int*)al(sizeof(int) * (N_NODES + 1));
    // ebuf (12.8 MB) is dead after k_bsort; xrel16 (32 MB) aliases it.
    uintptr_t big0 = al(sizeof(unsigned int) * (size_t)N_NODES * 80);
    int2*  ebuf    = (int2*)big0;
    unsigned int* xrel16 = (unsigned int*)big0;
    int2*  esort   = (int2*)al(sizeof(int2) * N_EDGES);
    unsigned short* Wbf = (unsigned short*)al(sizeof(unsigned short) * 192 * IN_FEATS);
    float* agg     = (float*)al(sizeof(float) * (size_t)N_NODES * 32);
    float* concat  = (float*)al(sizeof(float) * (size_t)N_NODES * 96);

    hipMemsetAsync(ghist, 0, sizeof(int) * NB, stream);

    k_bcount<<<BSCAT_BLOCKS, 256, 0, stream>>>(dst, ghist);
    k_bscan<<<1, 256, 0, stream>>>(ghist, bases, gcur);
    k_bscatter<<<BSCAT_BLOCKS, 256, 0, stream>>>(src, dst, etype, edge_mask, gcur, ebuf);
    k_bsort<<<NB, 1024, 0, stream>>>(bases, ebuf, esort, offsets);

    const int agrid = (N_NODES + 31) / 32;

    // layer 1
    k_prepw_bf<<<(192 * IN_FEATS + 255) / 256, 256, 0, stream>>>(V1, comp1, loop1, Wbf, IN_FEATS);
    k_transform_mfma<IN_FEATS><<<512, 256, 0, stream>>>(x, IN_FEATS, Wbf, b1, xrel16, agg);
    k_agg<<<agrid, 256, 0, stream>>>(offsets, esort, xrel16, agg, concat, 0);

    // layer 2
    k_prepw_bf<<<(192 * HID + 255) / 256, 256, 0, stream>>>(V2, comp2, loop2, Wbf, HID);
    k_transform_mfma<HID><<<512, 256, 0, stream>>>(concat + 0, 96, Wbf, b2, xrel16, agg);
    k_agg<<<agrid, 256, 0, stream>>>(offsets, esort, xrel16, agg, concat, 32);

    // layer 3
    k_prepw_bf<<<(192 * HID + 255) / 256, 256, 0, stream>>>(V3, comp3, loop3, Wbf, HID);
    k_transform_mfma<HID><<<512, 256, 0, stream>>>(concat + 32, 96, Wbf, b3, xrel16, agg);
    k_agg<<<agrid, 256, 0, stream>>>(offsets, esort, xrel16, agg, concat, 64);

    k_mlp<<<N_PAIRS, 128, 0, stream>>>(concat, users_idx, items_idx, w1, bw1, w2, bw2, out);
}